// Round 5
// baseline (108.765 us; speedup 1.0000x reference)
//
#include <hip/hip_runtime.h>
#include <hip/hip_fp16.h>

#define H    256
#define W    256
#define WH   129            // W/2 + 1
#define VLEN 182            // max radial bin + 1
#define NIMG 64             // 32 pred + 32 target
#define TWO_PI 6.283185307179586f
#define TSTRIDE 35          // LDS tile row stride (half2 units) for colfft
#define NBLK_COL 256        // colfft grid size (4 per image)

__device__ __forceinline__ int isqrt_exact(int s2) {
    int r = (int)sqrtf((float)s2);
    while ((r + 1) * (r + 1) <= s2) ++r;
    while (r * r > s2) --r;
    return r;
}

__device__ __forceinline__ float2 cmul(float2 a, float2 b) {
    return make_float2(a.x * b.x - a.y * b.y, a.x * b.y + a.y * b.x);
}

// 256-point DIF FFT held by one 64-lane wave; thread t owns positions
// i = t + 64r (r=0..3). On exit, position i holds X[bitrev8(i)].
__device__ __forceinline__ void wfft256(float2 z[4], int t) {
    float s, c;
    // m=256: reg pairs (0,2),(1,3); w = e^{-2pi i t/256}, pair(1,3) gets w*(-i)
    __sincosf(-TWO_PI * (1.0f / 256.0f) * (float)t, &s, &c);
    {
        const float2 w0 = make_float2(c, s);
        const float2 w1 = make_float2(s, -c);          // w0 * (-i)
        float2 u0 = z[0], v0 = z[2], u1 = z[1], v1 = z[3];
        z[0] = make_float2(u0.x + v0.x, u0.y + v0.y);
        z[2] = cmul(make_float2(u0.x - v0.x, u0.y - v0.y), w0);
        z[1] = make_float2(u1.x + v1.x, u1.y + v1.y);
        z[3] = cmul(make_float2(u1.x - v1.x, u1.y - v1.y), w1);
    }
    // m=128: reg pairs (0,1),(2,3); w = e^{-2pi i t/128}
    __sincosf(-TWO_PI * (1.0f / 128.0f) * (float)t, &s, &c);
    {
        const float2 w = make_float2(c, s);
        float2 u0 = z[0], v0 = z[1], u1 = z[2], v1 = z[3];
        z[0] = make_float2(u0.x + v0.x, u0.y + v0.y);
        z[1] = cmul(make_float2(u0.x - v0.x, u0.y - v0.y), w);
        z[2] = make_float2(u1.x + v1.x, u1.y + v1.y);
        z[3] = cmul(make_float2(u1.x - v1.x, u1.y - v1.y), w);
    }
    // m=64..8: lane-xor m/2, w = e^{-2pi i (t&(m/2-1))/m}
    #pragma unroll
    for (int m = 64; m >= 8; m >>= 1) {
        const int hm = m >> 1;
        __sincosf((-TWO_PI / (float)m) * (float)(t & (hm - 1)), &s, &c);
        const float2 w = make_float2(c, s);
        const bool hi = (t & hm) != 0;
        #pragma unroll
        for (int r = 0; r < 4; ++r) {
            float2 o;
            o.x = __shfl_xor(z[r].x, hm, 64);
            o.y = __shfl_xor(z[r].y, hm, 64);
            if (hi) z[r] = cmul(make_float2(o.x - z[r].x, o.y - z[r].y), w);
            else    z[r] = make_float2(z[r].x + o.x, z[r].y + o.y);
        }
    }
    // m=4: lane-xor 2; w = 1 (t even) or -i (t odd)
    {
        const bool hi  = (t & 2) != 0;
        const bool odd = (t & 1) != 0;
        #pragma unroll
        for (int r = 0; r < 4; ++r) {
            float2 o;
            o.x = __shfl_xor(z[r].x, 2, 64);
            o.y = __shfl_xor(z[r].y, 2, 64);
            float2 d = hi ? make_float2(o.x - z[r].x, o.y - z[r].y)
                          : make_float2(z[r].x + o.x, z[r].y + o.y);
            if (hi && odd) d = make_float2(d.y, -d.x);   // * (-i)
            z[r] = d;
        }
    }
    // m=2: lane-xor 1
    {
        const bool hi = (t & 1) != 0;
        #pragma unroll
        for (int r = 0; r < 4; ++r) {
            float2 o;
            o.x = __shfl_xor(z[r].x, 1, 64);
            o.y = __shfl_xor(z[r].y, 1, 64);
            z[r] = hi ? make_float2(o.x - z[r].x, o.y - z[r].y)
                      : make_float2(z[r].x + o.x, z[r].y + o.y);
        }
    }
}

// 4 waves/block; each wave: float4 luma for a packed row-pair, LDS relayout,
// wave FFT, LDS unpack of the two real spectra, fp16 store.
// Blocks with (b&31)==0 zero gsum; block 0 resets the completion counter.
__global__ __launch_bounds__(256)
void rowfft_wave(const float* __restrict__ pred, const float* __restrict__ targ,
                 __half2* __restrict__ G /* [NIMG][256][WH] */,
                 float* __restrict__ gsum /* [NIMG][VLEN] */,
                 unsigned* __restrict__ counter) {
    __shared__ float zbuf[4][512];     // per wave: re[256] + im[256]
    const int tid  = threadIdx.x;
    const int t    = tid & 63;
    const int wid  = tid >> 6;
    const int b    = blockIdx.x;       // 0..2047
    const int img  = b >> 5;           // 32 blocks per image
    const int pair = ((b & 31) << 2) | wid;
    const int rowA = pair * 2;

    if ((b & 31) == 0) {
        for (int v = tid; v < VLEN; v += 256) gsum[img * VLEN + v] = 0.0f;
    }
    if (b == 0 && tid == 0) *counter = 0u;

    const float* src  = (img < 32) ? pred : targ;
    const float* base = src + (size_t)(img & 31) * (3 * H * W) + (size_t)rowA * W;

    // Vector loads: 6 x dwordx4 per thread (2 rows x 3 channels).
    const float4 aR = reinterpret_cast<const float4*>(base)[t];
    const float4 aG = reinterpret_cast<const float4*>(base + H * W)[t];
    const float4 aB = reinterpret_cast<const float4*>(base + 2 * H * W)[t];
    const float4 bR = reinterpret_cast<const float4*>(base + W)[t];
    const float4 bG = reinterpret_cast<const float4*>(base + H * W + W)[t];
    const float4 bB = reinterpret_cast<const float4*>(base + 2 * H * W + W)[t];

    float* zr = zbuf[wid];
    float* zi = zr + 256;
    float4 ga4, gb4;
    ga4.x = 0.299f * aR.x + 0.587f * aG.x + 0.114f * aB.x;
    ga4.y = 0.299f * aR.y + 0.587f * aG.y + 0.114f * aB.y;
    ga4.z = 0.299f * aR.z + 0.587f * aG.z + 0.114f * aB.z;
    ga4.w = 0.299f * aR.w + 0.587f * aG.w + 0.114f * aB.w;
    gb4.x = 0.299f * bR.x + 0.587f * bG.x + 0.114f * bB.x;
    gb4.y = 0.299f * bR.y + 0.587f * bG.y + 0.114f * bB.y;
    gb4.z = 0.299f * bR.z + 0.587f * bG.z + 0.114f * bB.z;
    gb4.w = 0.299f * bR.w + 0.587f * bG.w + 0.114f * bB.w;
    reinterpret_cast<float4*>(zr)[t] = ga4;   // positions 4t..4t+3
    reinterpret_cast<float4*>(zi)[t] = gb4;
    __syncthreads();

    float2 z[4];
    #pragma unroll
    for (int r = 0; r < 4; ++r)
        z[r] = make_float2(zr[t + (r << 6)], zi[t + (r << 6)]);

    wfft256(z, t);

    __syncthreads();                   // zbuf reuse: all prior reads done
    #pragma unroll
    for (int r = 0; r < 4; ++r) {
        const int x  = (int)(__brev((unsigned)(t + (r << 6))) >> 24);
        const int sx = x ^ (x >> 5);
        zr[sx] = z[r].x; zi[sx] = z[r].y;
    }
    __syncthreads();

    // Unpack: Ga[k] = (Z[k]+conj(Z[-k]))/2, Gb[k] = -i(Z[k]-conj(Z[-k]))/2
    __half2* da = G + ((size_t)img * 256 + rowA) * WH;
    __half2* db = da + WH;
    for (int k = t; k <= 128; k += 64) {
        const int kq = (256 - k) & 255;
        const int sk = k ^ (k >> 5), sq = kq ^ (kq >> 5);
        const float2 P = make_float2(zr[sk], zi[sk]);
        const float2 Q = make_float2(zr[sq], zi[sq]);
        da[k] = __floats2half2_rn(0.5f * (P.x + Q.x), 0.5f * (P.y - Q.y));
        db[k] = __floats2half2_rn(0.5f * (P.y + Q.y), 0.5f * (Q.x - P.x));
    }
}

// 4 blocks per image (33/33/33/30 columns): stage fp16 tile in LDS, wave-FFT
// columns, fused log-power + radial binning, atomic flush. The LAST block to
// finish (completion counter) computes counts, normalizes, and writes the MSE.
__global__ __launch_bounds__(1024)
void colfft_bin_finish(const __half2* __restrict__ G,
                       float* __restrict__ gsum,
                       unsigned* __restrict__ counter,
                       float* __restrict__ out) {
    __shared__ __half2 tile[256 * TSTRIDE];
    __shared__ float bins[VLEN];
    __shared__ int   scnt[VLEN];
    __shared__ float facc[16];
    __shared__ int   amLast;
    const int tid = threadIdx.x;
    const int t   = tid & 63;
    const int wid = tid >> 6;          // 0..15
    const int blk = blockIdx.x;        // 0..255
    const int img = blk >> 2;
    const int q   = blk & 3;
    const int j0  = q * 33;
    const int nc  = (q < 3) ? 33 : 30;

    for (int v = tid; v < VLEN; v += 1024) bins[v] = 0.0f;

    const __half2* g = G + (size_t)img * 256 * WH;
    for (int e = tid; e < 256 * 33; e += 1024) {
        const int row = e / 33;
        const int cl  = e - row * 33;
        if (j0 + cl < WH)
            tile[row * TSTRIDE + cl] = g[row * WH + j0 + cl];
    }
    __syncthreads();

    for (int cl = wid; cl < nc; cl += 16) {
        const int j = j0 + cl;
        float2 z[4];
        #pragma unroll
        for (int r = 0; r < 4; ++r)
            z[r] = __half22float2(tile[(t + (r << 6)) * TSTRIDE + cl]);

        wfft256(z, t);

        const int j2 = j * j;
        #pragma unroll
        for (int r = 0; r < 4; ++r) {
            const int n   = (int)(__brev((unsigned)(t + (r << 6))) >> 24);
            const int di  = (n < 128) ? n : n - 256;
            const int rad = isqrt_exact(di * di + j2);
            const float p = z[r].x * z[r].x + z[r].y * z[r].y + 1e-8f;
            atomicAdd(&bins[rad], 20.0f * __logf(p));
        }
    }
    __syncthreads();

    const int jmax = j0 + nc - 1;
    const int rmax = isqrt_exact(128 * 128 + jmax * jmax);
    float* gs = gsum + (size_t)img * VLEN;
    for (int v = j0 + tid; v <= rmax; v += 1024)
        atomicAdd(&gs[v], bins[v]);

    // ---- completion protocol: last block finishes the reduction ----
    __threadfence();                   // publish this block's atomics
    __syncthreads();                   // all threads fenced
    if (tid == 0) {
        const unsigned old = atomicAdd(counter, 1u);
        amLast = (old == NBLK_COL - 1);
    }
    __syncthreads();
    if (!amLast) return;
    __threadfence();                   // acquire others' atomics

    // static radial-bin counts
    for (int v = tid; v < VLEN; v += 1024) scnt[v] = 0;
    __syncthreads();
    for (int e = tid; e < H * WH; e += 1024) {
        const int k  = e / WH;
        const int j  = e - k * WH;
        const int di = (k < 128) ? k : k - 256;
        atomicAdd(&scnt[isqrt_exact(di * di + j * j)], 1);
    }
    __syncthreads();

    float total = 0.0f;
    for (int pr = wid; pr < 32; pr += 16) {
        float a[3], b[3];
        float mna = 1e30f, mnb = 1e30f, mxa = -1e30f, mxb = -1e30f;
        #pragma unroll
        for (int r = 0; r < 3; ++r) {
            const int v = t + (r << 6);
            if (v < VLEN) {
                const float ic = 1.0f / (float)scnt[v];
                // device-scope atomic reads: safe across XCD L2s
                a[r] = atomicAdd(&gsum[(size_t)pr * VLEN + v], 0.0f) * ic;
                b[r] = atomicAdd(&gsum[(size_t)(pr + 32) * VLEN + v], 0.0f) * ic;
                mna = fminf(mna, a[r]); mxa = fmaxf(mxa, a[r]);
                mnb = fminf(mnb, b[r]); mxb = fmaxf(mxb, b[r]);
            } else { a[r] = 0.0f; b[r] = 0.0f; }
        }
        #pragma unroll
        for (int m = 32; m >= 1; m >>= 1) {
            mna = fminf(mna, __shfl_xor(mna, m, 64));
            mxa = fmaxf(mxa, __shfl_xor(mxa, m, 64));
            mnb = fminf(mnb, __shfl_xor(mnb, m, 64));
            mxb = fmaxf(mxb, __shfl_xor(mxb, m, 64));
        }
        const float inva = 1.0f / (mxa - mna);
        const float invb = 1.0f / (mxb - mnb);
        float sacc = 0.0f;
        #pragma unroll
        for (int r = 0; r < 3; ++r) {
            const int v = t + (r << 6);
            if (v < VLEN) {
                const float d = (a[r] - mna) * inva - (b[r] - mnb) * invb;
                sacc += d * d;
            }
        }
        #pragma unroll
        for (int m = 32; m >= 1; m >>= 1) sacc += __shfl_xor(sacc, m, 64);
        total += sacc;
    }
    if (t == 0) facc[wid] = total;
    __syncthreads();
    if (tid == 0) {
        float r = 0.0f;
        for (int i = 0; i < 16; ++i) r += facc[i];
        out[0] = r / (float)(32 * VLEN);
    }
}

extern "C" void kernel_launch(void* const* d_in, const int* in_sizes, int n_in,
                              void* d_out, int out_size, void* d_ws, size_t ws_size,
                              hipStream_t stream) {
    const float* pred = (const float*)d_in[0];
    const float* targ = (const float*)d_in[1];
    float* out = (float*)d_out;

    char* ws = (char*)d_ws;
    __half2* G = (__half2*)ws;                                   // NIMG*256*WH half2
    ws += (size_t)NIMG * 256 * WH * sizeof(__half2);
    float* gsum = (float*)ws;                                    // NIMG*VLEN floats
    ws += (size_t)NIMG * VLEN * sizeof(float);
    unsigned* counter = (unsigned*)ws;                           // 1 u32

    rowfft_wave<<<NIMG * 32, 256, 0, stream>>>(pred, targ, G, gsum, counter);
    colfft_bin_finish<<<NBLK_COL, 1024, 0, stream>>>(G, gsum, counter, out);
}

// Round 6
// 58.024 us; speedup vs baseline: 1.8745x; 1.8745x over previous
//
#include <hip/hip_runtime.h>
#include <hip/hip_fp16.h>

#define H    256
#define W    256
#define WH   129            // W/2 + 1
#define VLEN 182            // max radial bin + 1
#define NIMG 64             // 32 pred + 32 target
#define TWO_PI 6.283185307179586f
#define TSTRIDE 35          // LDS tile row stride (half2 units) for colfft

__device__ __forceinline__ int isqrt_exact(int s2) {
    int r = (int)sqrtf((float)s2);
    while ((r + 1) * (r + 1) <= s2) ++r;
    while (r * r > s2) --r;
    return r;
}

__device__ __forceinline__ float2 cmul(float2 a, float2 b) {
    return make_float2(a.x * b.x - a.y * b.y, a.x * b.y + a.y * b.x);
}

// 256-point DIF FFT held by one 64-lane wave; thread t owns positions
// i = t + 64r (r=0..3). On exit, position i holds X[bitrev8(i)].
__device__ __forceinline__ void wfft256(float2 z[4], int t) {
    float s, c;
    // m=256: reg pairs (0,2),(1,3); w = e^{-2pi i t/256}, pair(1,3) gets w*(-i)
    __sincosf(-TWO_PI * (1.0f / 256.0f) * (float)t, &s, &c);
    {
        const float2 w0 = make_float2(c, s);
        const float2 w1 = make_float2(s, -c);          // w0 * (-i)
        float2 u0 = z[0], v0 = z[2], u1 = z[1], v1 = z[3];
        z[0] = make_float2(u0.x + v0.x, u0.y + v0.y);
        z[2] = cmul(make_float2(u0.x - v0.x, u0.y - v0.y), w0);
        z[1] = make_float2(u1.x + v1.x, u1.y + v1.y);
        z[3] = cmul(make_float2(u1.x - v1.x, u1.y - v1.y), w1);
    }
    // m=128: reg pairs (0,1),(2,3); w = e^{-2pi i t/128}
    __sincosf(-TWO_PI * (1.0f / 128.0f) * (float)t, &s, &c);
    {
        const float2 w = make_float2(c, s);
        float2 u0 = z[0], v0 = z[1], u1 = z[2], v1 = z[3];
        z[0] = make_float2(u0.x + v0.x, u0.y + v0.y);
        z[1] = cmul(make_float2(u0.x - v0.x, u0.y - v0.y), w);
        z[2] = make_float2(u1.x + v1.x, u1.y + v1.y);
        z[3] = cmul(make_float2(u1.x - v1.x, u1.y - v1.y), w);
    }
    // m=64..8: lane-xor m/2, w = e^{-2pi i (t&(m/2-1))/m}
    #pragma unroll
    for (int m = 64; m >= 8; m >>= 1) {
        const int hm = m >> 1;
        __sincosf((-TWO_PI / (float)m) * (float)(t & (hm - 1)), &s, &c);
        const float2 w = make_float2(c, s);
        const bool hi = (t & hm) != 0;
        #pragma unroll
        for (int r = 0; r < 4; ++r) {
            float2 o;
            o.x = __shfl_xor(z[r].x, hm, 64);
            o.y = __shfl_xor(z[r].y, hm, 64);
            if (hi) z[r] = cmul(make_float2(o.x - z[r].x, o.y - z[r].y), w);
            else    z[r] = make_float2(z[r].x + o.x, z[r].y + o.y);
        }
    }
    // m=4: lane-xor 2; w = 1 (t even) or -i (t odd)
    {
        const bool hi  = (t & 2) != 0;
        const bool odd = (t & 1) != 0;
        #pragma unroll
        for (int r = 0; r < 4; ++r) {
            float2 o;
            o.x = __shfl_xor(z[r].x, 2, 64);
            o.y = __shfl_xor(z[r].y, 2, 64);
            float2 d = hi ? make_float2(o.x - z[r].x, o.y - z[r].y)
                          : make_float2(z[r].x + o.x, z[r].y + o.y);
            if (hi && odd) d = make_float2(d.y, -d.x);   // * (-i)
            z[r] = d;
        }
    }
    // m=2: lane-xor 1
    {
        const bool hi = (t & 1) != 0;
        #pragma unroll
        for (int r = 0; r < 4; ++r) {
            float2 o;
            o.x = __shfl_xor(z[r].x, 1, 64);
            o.y = __shfl_xor(z[r].y, 1, 64);
            z[r] = hi ? make_float2(o.x - z[r].x, o.y - z[r].y)
                      : make_float2(z[r].x + o.x, z[r].y + o.y);
        }
    }
}

// 4 waves/block; each wave: float4 luma for a packed row-pair, LDS relayout,
// wave FFT, LDS unpack of the two real spectra, fp16 store.
// Blocks with (b&31)==0 zero gsum; block 0 also computes static bin counts.
__global__ __launch_bounds__(256)
void rowfft_wave(const float* __restrict__ pred, const float* __restrict__ targ,
                 __half2* __restrict__ G /* [NIMG][256][WH] */,
                 float* __restrict__ gsum /* [NIMG][VLEN] */,
                 int* __restrict__ counts /* [VLEN] */) {
    __shared__ float zbuf[4][512];     // per wave: re[256] + im[256]
    __shared__ int   scnt[VLEN];
    const int tid  = threadIdx.x;
    const int t    = tid & 63;
    const int wid  = tid >> 6;
    const int b    = blockIdx.x;       // 0..2047
    const int img  = b >> 5;           // 32 blocks per image
    const int pair = ((b & 31) << 2) | wid;
    const int rowA = pair * 2;

    if ((b & 31) == 0) {
        for (int v = tid; v < VLEN; v += 256) gsum[img * VLEN + v] = 0.0f;
    }
    if (b == 0) {                      // uniform per-block branch
        for (int v = tid; v < VLEN; v += 256) scnt[v] = 0;
        __syncthreads();
        for (int e = tid; e < H * WH; e += 256) {
            const int k  = e / WH;
            const int j  = e - k * WH;
            const int di = (k < 128) ? k : k - 256;
            atomicAdd(&scnt[isqrt_exact(di * di + j * j)], 1);
        }
        __syncthreads();
        for (int v = tid; v < VLEN; v += 256) counts[v] = scnt[v];
    }

    const float* src  = (img < 32) ? pred : targ;
    const float* base = src + (size_t)(img & 31) * (3 * H * W) + (size_t)rowA * W;

    // Vector loads: 6 x dwordx4 per thread (2 rows x 3 channels).
    const float4 aR = reinterpret_cast<const float4*>(base)[t];
    const float4 aG = reinterpret_cast<const float4*>(base + H * W)[t];
    const float4 aB = reinterpret_cast<const float4*>(base + 2 * H * W)[t];
    const float4 bR = reinterpret_cast<const float4*>(base + W)[t];
    const float4 bG = reinterpret_cast<const float4*>(base + H * W + W)[t];
    const float4 bB = reinterpret_cast<const float4*>(base + 2 * H * W + W)[t];

    float* zr = zbuf[wid];
    float* zi = zr + 256;
    float4 ga4, gb4;
    ga4.x = 0.299f * aR.x + 0.587f * aG.x + 0.114f * aB.x;
    ga4.y = 0.299f * aR.y + 0.587f * aG.y + 0.114f * aB.y;
    ga4.z = 0.299f * aR.z + 0.587f * aG.z + 0.114f * aB.z;
    ga4.w = 0.299f * aR.w + 0.587f * aG.w + 0.114f * aB.w;
    gb4.x = 0.299f * bR.x + 0.587f * bG.x + 0.114f * bB.x;
    gb4.y = 0.299f * bR.y + 0.587f * bG.y + 0.114f * bB.y;
    gb4.z = 0.299f * bR.z + 0.587f * bG.z + 0.114f * bB.z;
    gb4.w = 0.299f * bR.w + 0.587f * bG.w + 0.114f * bB.w;
    reinterpret_cast<float4*>(zr)[t] = ga4;   // positions 4t..4t+3
    reinterpret_cast<float4*>(zi)[t] = gb4;
    __syncthreads();

    float2 z[4];
    #pragma unroll
    for (int r = 0; r < 4; ++r)
        z[r] = make_float2(zr[t + (r << 6)], zi[t + (r << 6)]);

    wfft256(z, t);

    __syncthreads();                   // zbuf reuse: all prior reads done
    #pragma unroll
    for (int r = 0; r < 4; ++r) {
        const int x  = (int)(__brev((unsigned)(t + (r << 6))) >> 24);
        const int sx = x ^ (x >> 5);
        zr[sx] = z[r].x; zi[sx] = z[r].y;
    }
    __syncthreads();

    // Unpack: Ga[k] = (Z[k]+conj(Z[-k]))/2, Gb[k] = -i(Z[k]-conj(Z[-k]))/2
    __half2* da = G + ((size_t)img * 256 + rowA) * WH;
    __half2* db = da + WH;
    for (int k = t; k <= 128; k += 64) {
        const int kq = (256 - k) & 255;
        const int sk = k ^ (k >> 5), sq = kq ^ (kq >> 5);
        const float2 P = make_float2(zr[sk], zi[sk]);
        const float2 Q = make_float2(zr[sq], zi[sq]);
        da[k] = __floats2half2_rn(0.5f * (P.x + Q.x), 0.5f * (P.y - Q.y));
        db[k] = __floats2half2_rn(0.5f * (P.y + Q.y), 0.5f * (Q.x - P.x));
    }
}

// 4 blocks per image (33/33/33/30 columns): stage fp16 tile in LDS, wave-FFT
// columns, fused log-power + radial binning, one atomic flush per block.
__global__ __launch_bounds__(1024)
void colfft_bin(const __half2* __restrict__ G, float* __restrict__ gsum) {
    __shared__ __half2 tile[256 * TSTRIDE];
    __shared__ float bins[VLEN];
    const int tid = threadIdx.x;
    const int t   = tid & 63;
    const int wid = tid >> 6;          // 0..15
    const int blk = blockIdx.x;        // 0..255
    const int img = blk >> 2;
    const int q   = blk & 3;
    const int j0  = q * 33;
    const int nc  = (q < 3) ? 33 : 30;

    for (int v = tid; v < VLEN; v += 1024) bins[v] = 0.0f;

    const __half2* g = G + (size_t)img * 256 * WH;
    for (int e = tid; e < 256 * 33; e += 1024) {
        const int row = e / 33;
        const int cl  = e - row * 33;
        if (j0 + cl < WH)
            tile[row * TSTRIDE + cl] = g[row * WH + j0 + cl];
    }
    __syncthreads();

    for (int cl = wid; cl < nc; cl += 16) {
        const int j = j0 + cl;
        float2 z[4];
        #pragma unroll
        for (int r = 0; r < 4; ++r)
            z[r] = __half22float2(tile[(t + (r << 6)) * TSTRIDE + cl]);

        wfft256(z, t);

        const int j2 = j * j;
        #pragma unroll
        for (int r = 0; r < 4; ++r) {
            const int n   = (int)(__brev((unsigned)(t + (r << 6))) >> 24);
            const int di  = (n < 128) ? n : n - 256;
            const int rad = isqrt_exact(di * di + j2);
            const float p = z[r].x * z[r].x + z[r].y * z[r].y + 1e-8f;
            atomicAdd(&bins[rad], 20.0f * __logf(p));
        }
    }
    __syncthreads();

    const int jmax = j0 + nc - 1;
    const int rmax = isqrt_exact(128 * 128 + jmax * jmax);
    float* gs = gsum + (size_t)img * VLEN;
    for (int v = j0 + tid; v <= rmax; v += 1024)
        atomicAdd(&gs[v], bins[v]);
}

// One block: per-pair mean, min/max normalize, MSE -> out (counts precomputed).
__global__ __launch_bounds__(1024)
void finish1(const float* __restrict__ gsum, const int* __restrict__ counts,
             float* __restrict__ out) {
    __shared__ float facc[16];
    const int tid = threadIdx.x;
    const int t   = tid & 63;
    const int wid = tid >> 6;

    float total = 0.0f;
    for (int pr = wid; pr < 32; pr += 16) {
        float a[3], b[3];
        float mna = 1e30f, mnb = 1e30f, mxa = -1e30f, mxb = -1e30f;
        #pragma unroll
        for (int r = 0; r < 3; ++r) {
            const int v = t + (r << 6);
            if (v < VLEN) {
                const float ic = 1.0f / (float)counts[v];
                a[r] = gsum[(size_t)pr * VLEN + v] * ic;
                b[r] = gsum[(size_t)(pr + 32) * VLEN + v] * ic;
                mna = fminf(mna, a[r]); mxa = fmaxf(mxa, a[r]);
                mnb = fminf(mnb, b[r]); mxb = fmaxf(mxb, b[r]);
            } else { a[r] = 0.0f; b[r] = 0.0f; }
        }
        #pragma unroll
        for (int m = 32; m >= 1; m >>= 1) {
            mna = fminf(mna, __shfl_xor(mna, m, 64));
            mxa = fmaxf(mxa, __shfl_xor(mxa, m, 64));
            mnb = fminf(mnb, __shfl_xor(mnb, m, 64));
            mxb = fmaxf(mxb, __shfl_xor(mxb, m, 64));
        }
        const float inva = 1.0f / (mxa - mna);
        const float invb = 1.0f / (mxb - mnb);
        float sacc = 0.0f;
        #pragma unroll
        for (int r = 0; r < 3; ++r) {
            const int v = t + (r << 6);
            if (v < VLEN) {
                const float d = (a[r] - mna) * inva - (b[r] - mnb) * invb;
                sacc += d * d;
            }
        }
        #pragma unroll
        for (int m = 32; m >= 1; m >>= 1) sacc += __shfl_xor(sacc, m, 64);
        total += sacc;
    }
    if (t == 0) facc[wid] = total;
    __syncthreads();
    if (tid == 0) {
        float r = 0.0f;
        for (int i = 0; i < 16; ++i) r += facc[i];
        out[0] = r / (float)(32 * VLEN);
    }
}

extern "C" void kernel_launch(void* const* d_in, const int* in_sizes, int n_in,
                              void* d_out, int out_size, void* d_ws, size_t ws_size,
                              hipStream_t stream) {
    const float* pred = (const float*)d_in[0];
    const float* targ = (const float*)d_in[1];
    float* out = (float*)d_out;

    char* ws = (char*)d_ws;
    __half2* G = (__half2*)ws;                                   // NIMG*256*WH half2
    ws += (size_t)NIMG * 256 * WH * sizeof(__half2);
    float* gsum = (float*)ws;                                    // NIMG*VLEN floats
    ws += (size_t)NIMG * VLEN * sizeof(float);
    int* counts = (int*)ws;                                      // VLEN ints

    rowfft_wave<<<NIMG * 32, 256, 0, stream>>>(pred, targ, G, gsum, counts);
    colfft_bin<<<NIMG * 4, 1024, 0, stream>>>(G, gsum);
    finish1<<<1, 1024, 0, stream>>>(gsum, counts, out);
}

// Round 7
// 51.281 us; speedup vs baseline: 2.1209x; 1.1315x over previous
//
#include <hip/hip_runtime.h>
#include <hip/hip_fp16.h>

#define H    256
#define W    256
#define WH   129            // W/2 + 1
#define VLEN 182            // max radial bin + 1
#define NIMG 64             // 32 pred + 32 target
#define TWO_PI 6.283185307179586f

__device__ __forceinline__ int isqrt_exact(int s2) {
    int r = (int)sqrtf((float)s2);
    while ((r + 1) * (r + 1) <= s2) ++r;
    while (r * r > s2) --r;
    return r;
}

__device__ __forceinline__ float2 cmul(float2 a, float2 b) {
    return make_float2(a.x * b.x - a.y * b.y, a.x * b.y + a.y * b.x);
}

// 256-point DIF FFT held by one 64-lane wave; thread t owns positions
// i = t + 64r (r=0..3). On exit, position i holds X[bitrev8(i)].
__device__ __forceinline__ void wfft256(float2 z[4], int t) {
    float s, c;
    // m=256: reg pairs (0,2),(1,3); w = e^{-2pi i t/256}, pair(1,3) gets w*(-i)
    __sincosf(-TWO_PI * (1.0f / 256.0f) * (float)t, &s, &c);
    {
        const float2 w0 = make_float2(c, s);
        const float2 w1 = make_float2(s, -c);          // w0 * (-i)
        float2 u0 = z[0], v0 = z[2], u1 = z[1], v1 = z[3];
        z[0] = make_float2(u0.x + v0.x, u0.y + v0.y);
        z[2] = cmul(make_float2(u0.x - v0.x, u0.y - v0.y), w0);
        z[1] = make_float2(u1.x + v1.x, u1.y + v1.y);
        z[3] = cmul(make_float2(u1.x - v1.x, u1.y - v1.y), w1);
    }
    // m=128: reg pairs (0,1),(2,3); w = e^{-2pi i t/128}
    __sincosf(-TWO_PI * (1.0f / 128.0f) * (float)t, &s, &c);
    {
        const float2 w = make_float2(c, s);
        float2 u0 = z[0], v0 = z[1], u1 = z[2], v1 = z[3];
        z[0] = make_float2(u0.x + v0.x, u0.y + v0.y);
        z[1] = cmul(make_float2(u0.x - v0.x, u0.y - v0.y), w);
        z[2] = make_float2(u1.x + v1.x, u1.y + v1.y);
        z[3] = cmul(make_float2(u1.x - v1.x, u1.y - v1.y), w);
    }
    // m=64..8: lane-xor m/2, w = e^{-2pi i (t&(m/2-1))/m}
    #pragma unroll
    for (int m = 64; m >= 8; m >>= 1) {
        const int hm = m >> 1;
        __sincosf((-TWO_PI / (float)m) * (float)(t & (hm - 1)), &s, &c);
        const float2 w = make_float2(c, s);
        const bool hi = (t & hm) != 0;
        #pragma unroll
        for (int r = 0; r < 4; ++r) {
            float2 o;
            o.x = __shfl_xor(z[r].x, hm, 64);
            o.y = __shfl_xor(z[r].y, hm, 64);
            if (hi) z[r] = cmul(make_float2(o.x - z[r].x, o.y - z[r].y), w);
            else    z[r] = make_float2(z[r].x + o.x, z[r].y + o.y);
        }
    }
    // m=4: lane-xor 2; w = 1 (t even) or -i (t odd)
    {
        const bool hi  = (t & 2) != 0;
        const bool odd = (t & 1) != 0;
        #pragma unroll
        for (int r = 0; r < 4; ++r) {
            float2 o;
            o.x = __shfl_xor(z[r].x, 2, 64);
            o.y = __shfl_xor(z[r].y, 2, 64);
            float2 d = hi ? make_float2(o.x - z[r].x, o.y - z[r].y)
                          : make_float2(z[r].x + o.x, z[r].y + o.y);
            if (hi && odd) d = make_float2(d.y, -d.x);   // * (-i)
            z[r] = d;
        }
    }
    // m=2: lane-xor 1
    {
        const bool hi = (t & 1) != 0;
        #pragma unroll
        for (int r = 0; r < 4; ++r) {
            float2 o;
            o.x = __shfl_xor(z[r].x, 1, 64);
            o.y = __shfl_xor(z[r].y, 1, 64);
            z[r] = hi ? make_float2(o.x - z[r].x, o.y - z[r].y)
                      : make_float2(z[r].x + o.x, z[r].y + o.y);
        }
    }
}

// 4 waves/block; each wave: coalesced scalar luma loads for a packed row-pair
// straight into registers, wave FFT, LDS unpack of the two real spectra,
// TRANSPOSED fp16 store: GT[img][k][row], row-pair packed as one 8B store.
// Blocks with (b&31)==0 zero gsum for their image.
__global__ __launch_bounds__(256)
void rowfft_wave(const float* __restrict__ pred, const float* __restrict__ targ,
                 uint2* __restrict__ GT /* [NIMG][WH][128] uint2 = row-pair */,
                 float* __restrict__ gsum /* [NIMG][VLEN] */) {
    __shared__ float zbuf[4][512];     // per wave: re[256] + im[256], swizzled
    const int tid  = threadIdx.x;
    const int t    = tid & 63;
    const int wid  = tid >> 6;
    const int b    = blockIdx.x;       // 0..2047
    const int img  = b >> 5;           // 32 blocks per image
    const int pair = ((b & 31) << 2) | wid;
    const int rowA = pair * 2;

    if ((b & 31) == 0) {
        for (int v = tid; v < VLEN; v += 256) gsum[img * VLEN + v] = 0.0f;
    }

    const float* src  = (img < 32) ? pred : targ;
    const float* base = src + (size_t)(img & 31) * (3 * H * W) + (size_t)rowA * W;

    float2 z[4];
    #pragma unroll
    for (int r = 0; r < 4; ++r) {
        const int n = t + (r << 6);
        const float ga = 0.299f * base[n]
                       + 0.587f * base[H * W + n]
                       + 0.114f * base[2 * H * W + n];
        const float gb = 0.299f * base[W + n]
                       + 0.587f * base[H * W + W + n]
                       + 0.114f * base[2 * H * W + W + n];
        z[r] = make_float2(ga, gb);
    }

    wfft256(z, t);

    float* zr = zbuf[wid];
    float* zi = zr + 256;
    #pragma unroll
    for (int r = 0; r < 4; ++r) {
        const int x  = (int)(__brev((unsigned)(t + (r << 6))) >> 24);
        const int sx = x ^ (x >> 5);
        zr[sx] = z[r].x; zi[sx] = z[r].y;
    }
    __syncthreads();

    // Unpack: Ga[k] = (Z[k]+conj(Z[-k]))/2, Gb[k] = -i(Z[k]-conj(Z[-k]))/2
    uint2* dst = GT + (size_t)img * WH * 128;
    for (int k = t; k <= 128; k += 64) {
        const int kq = (256 - k) & 255;
        const int sk = k ^ (k >> 5), sq = kq ^ (kq >> 5);
        const float2 P = make_float2(zr[sk], zi[sk]);
        const float2 Q = make_float2(zr[sq], zi[sq]);
        const __half2 a  = __floats2half2_rn(0.5f * (P.x + Q.x), 0.5f * (P.y - Q.y));
        const __half2 bb = __floats2half2_rn(0.5f * (P.y + Q.y), 0.5f * (Q.x - P.x));
        uint2 pk;
        pk.x = __builtin_bit_cast(unsigned, a);
        pk.y = __builtin_bit_cast(unsigned, bb);
        dst[(size_t)k * 128 + pair] = pk;   // rows (2*pair, 2*pair+1) at col k
    }
}

// 4 waves/block, one column-FFT per wave, coalesced loads from transposed GT.
// No tile staging. Fused log-power + radial binning into block-shared bins,
// one atomic flush per block.
__global__ __launch_bounds__(256)
void colfft_bin_t(const __half2* __restrict__ GT, float* __restrict__ gsum) {
    __shared__ float bins[VLEN];
    const int tid = threadIdx.x;
    const int t   = tid & 63;
    const int wid = tid >> 6;          // 0..3
    const int blk = blockIdx.x;        // 0..NIMG*33-1
    const int img = blk / 33;
    const int grp = blk - img * 33;
    const int j   = grp * 4 + wid;     // 0..131

    for (int v = tid; v < VLEN; v += 256) bins[v] = 0.0f;
    __syncthreads();

    if (j < WH) {
        const __half2* col = GT + ((size_t)img * WH + j) * 256;
        float2 z[4];
        #pragma unroll
        for (int r = 0; r < 4; ++r)
            z[r] = __half22float2(col[t + (r << 6)]);

        wfft256(z, t);

        const int j2 = j * j;
        #pragma unroll
        for (int r = 0; r < 4; ++r) {
            const int n   = (int)(__brev((unsigned)(t + (r << 6))) >> 24);
            const int di  = (n < 128) ? n : n - 256;
            const int rad = isqrt_exact(di * di + j2);
            const float p = z[r].x * z[r].x + z[r].y * z[r].y + 1e-8f;
            atomicAdd(&bins[rad], 20.0f * __logf(p));
        }
    }
    __syncthreads();

    const int jmax = (grp * 4 + 3 < WH) ? grp * 4 + 3 : WH - 1;
    const int rmax = isqrt_exact(128 * 128 + jmax * jmax);
    float* gs = gsum + (size_t)img * VLEN;
    for (int v = grp * 4 + tid; v <= rmax; v += 256)
        atomicAdd(&gs[v], bins[v]);
}

// One block: static bin counts, per-pair mean, min/max normalize, MSE -> out.
__global__ __launch_bounds__(1024)
void finish1(const float* __restrict__ gsum, float* __restrict__ out) {
    __shared__ int   scnt[VLEN];
    __shared__ float facc[16];
    const int tid = threadIdx.x;
    const int t   = tid & 63;
    const int wid = tid >> 6;

    for (int v = tid; v < VLEN; v += 1024) scnt[v] = 0;
    __syncthreads();
    for (int e = tid; e < H * WH; e += 1024) {
        const int k  = e / WH;
        const int j  = e - k * WH;
        const int di = (k < 128) ? k : k - 256;
        atomicAdd(&scnt[isqrt_exact(di * di + j * j)], 1);
    }
    __syncthreads();

    float total = 0.0f;
    for (int pr = wid; pr < 32; pr += 16) {
        float a[3], b[3];
        float mna = 1e30f, mnb = 1e30f, mxa = -1e30f, mxb = -1e30f;
        #pragma unroll
        for (int r = 0; r < 3; ++r) {
            const int v = t + (r << 6);
            if (v < VLEN) {
                const float ic = 1.0f / (float)scnt[v];
                a[r] = gsum[(size_t)pr * VLEN + v] * ic;
                b[r] = gsum[(size_t)(pr + 32) * VLEN + v] * ic;
                mna = fminf(mna, a[r]); mxa = fmaxf(mxa, a[r]);
                mnb = fminf(mnb, b[r]); mxb = fmaxf(mxb, b[r]);
            } else { a[r] = 0.0f; b[r] = 0.0f; }
        }
        #pragma unroll
        for (int m = 32; m >= 1; m >>= 1) {
            mna = fminf(mna, __shfl_xor(mna, m, 64));
            mxa = fmaxf(mxa, __shfl_xor(mxa, m, 64));
            mnb = fminf(mnb, __shfl_xor(mnb, m, 64));
            mxb = fmaxf(mxb, __shfl_xor(mxb, m, 64));
        }
        const float inva = 1.0f / (mxa - mna);
        const float invb = 1.0f / (mxb - mnb);
        float sacc = 0.0f;
        #pragma unroll
        for (int r = 0; r < 3; ++r) {
            const int v = t + (r << 6);
            if (v < VLEN) {
                const float d = (a[r] - mna) * inva - (b[r] - mnb) * invb;
                sacc += d * d;
            }
        }
        #pragma unroll
        for (int m = 32; m >= 1; m >>= 1) sacc += __shfl_xor(sacc, m, 64);
        total += sacc;
    }
    if (t == 0) facc[wid] = total;
    __syncthreads();
    if (tid == 0) {
        float r = 0.0f;
        for (int i = 0; i < 16; ++i) r += facc[i];
        out[0] = r / (float)(32 * VLEN);
    }
}

extern "C" void kernel_launch(void* const* d_in, const int* in_sizes, int n_in,
                              void* d_out, int out_size, void* d_ws, size_t ws_size,
                              hipStream_t stream) {
    const float* pred = (const float*)d_in[0];
    const float* targ = (const float*)d_in[1];
    float* out = (float*)d_out;

    char* ws = (char*)d_ws;
    uint2* GT = (uint2*)ws;                                      // NIMG*WH*128 uint2
    ws += (size_t)NIMG * WH * 128 * sizeof(uint2);
    float* gsum = (float*)ws;                                    // NIMG*VLEN floats

    rowfft_wave<<<NIMG * 32, 256, 0, stream>>>(pred, targ, GT, gsum);
    colfft_bin_t<<<NIMG * 33, 256, 0, stream>>>((const __half2*)GT, gsum);
    finish1<<<1, 1024, 0, stream>>>(gsum, out);
}

// Round 12
// 49.898 us; speedup vs baseline: 2.1798x; 1.0277x over previous
//
#include <hip/hip_runtime.h>
#include <hip/hip_fp16.h>

#define H    256
#define W    256
#define WH   129            // W/2 + 1
#define VLEN 182            // max radial bin + 1
#define NIMG 64             // 32 pred + 32 target
#define TWO_PI 6.283185307179586f

// Integer-exact floor(sqrt) for s2 <= 32768: v_sqrt_f32 (raw HW) -> trunc is
// off by at most 1; two branchless fixups.
__device__ __forceinline__ int isqrt_fast(int s2) {
    int r = (int)__builtin_amdgcn_sqrtf((float)s2);
    r -= (r * r > s2);
    r += ((r + 1) * (r + 1) <= s2);
    return r;
}

__device__ __forceinline__ float2 cmul(float2 a, float2 b) {
    return make_float2(a.x * b.x - a.y * b.y, a.x * b.y + a.y * b.x);
}

// 256-point DIF FFT held by one 64-lane wave; thread t owns positions
// i = t + 64r (r=0..3). On exit, position i holds X[bitrev8(i)].
__device__ __forceinline__ void wfft256(float2 z[4], int t) {
    float s, c;
    // m=256: reg pairs (0,2),(1,3); w = e^{-2pi i t/256}, pair(1,3) gets w*(-i)
    __sincosf(-TWO_PI * (1.0f / 256.0f) * (float)t, &s, &c);
    {
        const float2 w0 = make_float2(c, s);
        const float2 w1 = make_float2(s, -c);          // w0 * (-i)
        float2 u0 = z[0], v0 = z[2], u1 = z[1], v1 = z[3];
        z[0] = make_float2(u0.x + v0.x, u0.y + v0.y);
        z[2] = cmul(make_float2(u0.x - v0.x, u0.y - v0.y), w0);
        z[1] = make_float2(u1.x + v1.x, u1.y + v1.y);
        z[3] = cmul(make_float2(u1.x - v1.x, u1.y - v1.y), w1);
    }
    // m=128: reg pairs (0,1),(2,3); w = e^{-2pi i t/128}
    __sincosf(-TWO_PI * (1.0f / 128.0f) * (float)t, &s, &c);
    {
        const float2 w = make_float2(c, s);
        float2 u0 = z[0], v0 = z[1], u1 = z[2], v1 = z[3];
        z[0] = make_float2(u0.x + v0.x, u0.y + v0.y);
        z[1] = cmul(make_float2(u0.x - v0.x, u0.y - v0.y), w);
        z[2] = make_float2(u1.x + v1.x, u1.y + v1.y);
        z[3] = cmul(make_float2(u1.x - v1.x, u1.y - v1.y), w);
    }
    // m=64..8: lane-xor m/2, w = e^{-2pi i (t&(m/2-1))/m}
    #pragma unroll
    for (int m = 64; m >= 8; m >>= 1) {
        const int hm = m >> 1;
        __sincosf((-TWO_PI / (float)m) * (float)(t & (hm - 1)), &s, &c);
        const float2 w = make_float2(c, s);
        const bool hi = (t & hm) != 0;
        #pragma unroll
        for (int r = 0; r < 4; ++r) {
            float2 o;
            o.x = __shfl_xor(z[r].x, hm, 64);
            o.y = __shfl_xor(z[r].y, hm, 64);
            if (hi) z[r] = cmul(make_float2(o.x - z[r].x, o.y - z[r].y), w);
            else    z[r] = make_float2(z[r].x + o.x, z[r].y + o.y);
        }
    }
    // m=4: lane-xor 2; w = 1 (t even) or -i (t odd)
    {
        const bool hi  = (t & 2) != 0;
        const bool odd = (t & 1) != 0;
        #pragma unroll
        for (int r = 0; r < 4; ++r) {
            float2 o;
            o.x = __shfl_xor(z[r].x, 2, 64);
            o.y = __shfl_xor(z[r].y, 2, 64);
            float2 d = hi ? make_float2(o.x - z[r].x, o.y - z[r].y)
                          : make_float2(z[r].x + o.x, z[r].y + o.y);
            if (hi && odd) d = make_float2(d.y, -d.x);   // * (-i)
            z[r] = d;
        }
    }
    // m=2: lane-xor 1
    {
        const bool hi = (t & 1) != 0;
        #pragma unroll
        for (int r = 0; r < 4; ++r) {
            float2 o;
            o.x = __shfl_xor(z[r].x, 1, 64);
            o.y = __shfl_xor(z[r].y, 1, 64);
            z[r] = hi ? make_float2(o.x - z[r].x, o.y - z[r].y)
                      : make_float2(z[r].x + o.x, z[r].y + o.y);
        }
    }
}

// 4 waves/block; each wave: coalesced nontemporal luma loads for a packed
// row-pair, wave FFT, per-wave LDS stash; then BLOCK-COOPERATIVE unpack +
// coalesced transposed store: lanes e -> (k=e>>2, pair=e&3), so 4 consecutive
// pairs per k give 32B-contiguous segments (16 lines/instr instead of 64).
__global__ __launch_bounds__(256)
void rowfft_wave(const float* __restrict__ pred, const float* __restrict__ targ,
                 uint2* __restrict__ GT /* [NIMG][WH][128] uint2 = row-pair */,
                 float* __restrict__ gsum /* [NIMG][VLEN] */) {
    __shared__ float zbuf[4][512];     // per wave: re[256] + im[256], swizzled
    const int tid  = threadIdx.x;
    const int t    = tid & 63;
    const int wid  = tid >> 6;
    const int b    = blockIdx.x;       // 0..2047
    const int img  = b >> 5;           // 32 blocks per image
    const int pair = ((b & 31) << 2) | wid;
    const int rowA = pair * 2;

    if ((b & 31) == 0) {
        for (int v = tid; v < VLEN; v += 256) gsum[img * VLEN + v] = 0.0f;
    }

    const float* src  = (img < 32) ? pred : targ;
    const float* base = src + (size_t)(img & 31) * (3 * H * W) + (size_t)rowA * W;

    float2 z[4];
    #pragma unroll
    for (int r = 0; r < 4; ++r) {
        const int n = t + (r << 6);
        const float aR = __builtin_nontemporal_load(base + n);
        const float aG = __builtin_nontemporal_load(base + H * W + n);
        const float aB = __builtin_nontemporal_load(base + 2 * H * W + n);
        const float bR = __builtin_nontemporal_load(base + W + n);
        const float bG = __builtin_nontemporal_load(base + H * W + W + n);
        const float bB = __builtin_nontemporal_load(base + 2 * H * W + W + n);
        z[r] = make_float2(0.299f * aR + 0.587f * aG + 0.114f * aB,
                           0.299f * bR + 0.587f * bG + 0.114f * bB);
    }

    wfft256(z, t);

    float* zr = zbuf[wid];
    float* zi = zr + 256;
    #pragma unroll
    for (int r = 0; r < 4; ++r) {
        const int x  = (int)(__brev((unsigned)(t + (r << 6))) >> 24);
        const int sx = x ^ (x >> 5);
        zr[sx] = z[r].x; zi[sx] = z[r].y;
    }
    __syncthreads();                   // all 4 waves' spectra visible

    // Block-cooperative unpack + store:
    // Ga[k] = (Z[k]+conj(Z[-k]))/2, Gb[k] = -i(Z[k]-conj(Z[-k]))/2
    uint2* dst = GT + (size_t)img * WH * 128;
    const int basePair = (b & 31) << 2;
    for (int e = tid; e < WH * 4; e += 256) {
        const int k  = e >> 2;
        const int lp = e & 3;
        const float* qr = zbuf[lp];
        const float* qi = qr + 256;
        const int kq = (256 - k) & 255;
        const int sk = k ^ (k >> 5), sq = kq ^ (kq >> 5);
        const float2 P = make_float2(qr[sk], qi[sk]);
        const float2 Q = make_float2(qr[sq], qi[sq]);
        const __half2 a  = __floats2half2_rn(0.5f * (P.x + Q.x), 0.5f * (P.y - Q.y));
        const __half2 bb = __floats2half2_rn(0.5f * (P.y + Q.y), 0.5f * (Q.x - P.x));
        uint2 pk;
        pk.x = __builtin_bit_cast(unsigned, a);
        pk.y = __builtin_bit_cast(unsigned, bb);
        dst[(size_t)k * 128 + basePair + lp] = pk;
    }
}

// 4 waves/block, one column-FFT per wave, coalesced loads from transposed GT.
// Fused log-power + radial binning into block-shared bins, one atomic flush.
__global__ __launch_bounds__(256)
void colfft_bin_t(const __half2* __restrict__ GT, float* __restrict__ gsum) {
    __shared__ float bins[VLEN];
    const int tid = threadIdx.x;
    const int t   = tid & 63;
    const int wid = tid >> 6;          // 0..3
    const int blk = blockIdx.x;        // 0..NIMG*33-1
    const int img = blk / 33;
    const int grp = blk - img * 33;
    const int j   = grp * 4 + wid;     // 0..131

    for (int v = tid; v < VLEN; v += 256) bins[v] = 0.0f;
    __syncthreads();

    if (j < WH) {
        const __half2* col = GT + ((size_t)img * WH + j) * 256;
        float2 z[4];
        #pragma unroll
        for (int r = 0; r < 4; ++r)
            z[r] = __half22float2(col[t + (r << 6)]);

        wfft256(z, t);

        const int j2 = j * j;
        #pragma unroll
        for (int r = 0; r < 4; ++r) {
            const int n   = (int)(__brev((unsigned)(t + (r << 6))) >> 24);
            const int di  = (n < 128) ? n : n - 256;
            const int rad = isqrt_fast(di * di + j2);
            const float p = z[r].x * z[r].x + z[r].y * z[r].y + 1e-8f;
            atomicAdd(&bins[rad], 20.0f * __logf(p));
        }
    }
    __syncthreads();

    const int jmax = (grp * 4 + 3 < WH) ? grp * 4 + 3 : WH - 1;
    const int rmax = isqrt_fast(128 * 128 + jmax * jmax);
    float* gs = gsum + (size_t)img * VLEN;
    for (int v = grp * 4 + tid; v <= rmax; v += 256)
        atomicAdd(&gs[v], bins[v]);
}

// One block: static bin counts, per-pair mean, min/max normalize, MSE -> out.
__global__ __launch_bounds__(1024)
void finish1(const float* __restrict__ gsum, float* __restrict__ out) {
    __shared__ int   scnt[VLEN];
    __shared__ float facc[16];
    const int tid = threadIdx.x;
    const int t   = tid & 63;
    const int wid = tid >> 6;

    for (int v = tid; v < VLEN; v += 1024) scnt[v] = 0;
    __syncthreads();
    for (int e = tid; e < H * WH; e += 1024) {
        const int k  = e / WH;
        const int j  = e - k * WH;
        const int di = (k < 128) ? k : k - 256;
        atomicAdd(&scnt[isqrt_fast(di * di + j * j)], 1);
    }
    __syncthreads();

    float total = 0.0f;
    for (int pr = wid; pr < 32; pr += 16) {
        float a[3], b[3];
        float mna = 1e30f, mnb = 1e30f, mxa = -1e30f, mxb = -1e30f;
        #pragma unroll
        for (int r = 0; r < 3; ++r) {
            const int v = t + (r << 6);
            if (v < VLEN) {
                const float ic = 1.0f / (float)scnt[v];
                a[r] = gsum[(size_t)pr * VLEN + v] * ic;
                b[r] = gsum[(size_t)(pr + 32) * VLEN + v] * ic;
                mna = fminf(mna, a[r]); mxa = fmaxf(mxa, a[r]);
                mnb = fminf(mnb, b[r]); mxb = fmaxf(mxb, b[r]);
            } else { a[r] = 0.0f; b[r] = 0.0f; }
        }
        #pragma unroll
        for (int m = 32; m >= 1; m >>= 1) {
            mna = fminf(mna, __shfl_xor(mna, m, 64));
            mxa = fmaxf(mxa, __shfl_xor(mxa, m, 64));
            mnb = fminf(mnb, __shfl_xor(mnb, m, 64));
            mxb = fmaxf(mxb, __shfl_xor(mxb, m, 64));
        }
        const float inva = 1.0f / (mxa - mna);
        const float invb = 1.0f / (mxb - mnb);
        float sacc = 0.0f;
        #pragma unroll
        for (int r = 0; r < 3; ++r) {
            const int v = t + (r << 6);
            if (v < VLEN) {
                const float d = (a[r] - mna) * inva - (b[r] - mnb) * invb;
                sacc += d * d;
            }
        }
        #pragma unroll
        for (int m = 32; m >= 1; m >>= 1) sacc += __shfl_xor(sacc, m, 64);
        total += sacc;
    }
    if (t == 0) facc[wid] = total;
    __syncthreads();
    if (tid == 0) {
        float r = 0.0f;
        for (int i = 0; i < 16; ++i) r += facc[i];
        out[0] = r / (float)(32 * VLEN);
    }
}

extern "C" void kernel_launch(void* const* d_in, const int* in_sizes, int n_in,
                              void* d_out, int out_size, void* d_ws, size_t ws_size,
                              hipStream_t stream) {
    const float* pred = (const float*)d_in[0];
    const float* targ = (const float*)d_in[1];
    float* out = (float*)d_out;

    char* ws = (char*)d_ws;
    uint2* GT = (uint2*)ws;                                      // NIMG*WH*128 uint2
    ws += (size_t)NIMG * WH * 128 * sizeof(uint2);
    float* gsum = (float*)ws;                                    // NIMG*VLEN floats

    rowfft_wave<<<NIMG * 32, 256, 0, stream>>>(pred, targ, GT, gsum);
    colfft_bin_t<<<NIMG * 33, 256, 0, stream>>>((const __half2*)GT, gsum);
    finish1<<<1, 1024, 0, stream>>>(gsum, out);
}